// Round 1
// baseline (187.824 us; speedup 1.0000x reference)
//
#include <hip/hip_runtime.h>
#include <math.h>

#define NMODES 6400
#define CHUNKS 8
#define CHUNK  800   // NMODES / CHUNKS
#define TB     256

static __device__ __forceinline__ float softplusf(float x) {
    // jax.nn.softplus(x) = log1p(exp(-|x|)) + max(x, 0)
    return log1pf(expf(-fabsf(x))) + fmaxf(x, 0.0f);
}
static __device__ __forceinline__ float sigmoidf(float x) {
    return 1.0f / (1.0f + expf(-x));
}

__global__ void zero_kernel(float* __restrict__ out, int T) {
    int i = blockIdx.x * blockDim.x + threadIdx.x;
    if (i < T) out[i] = 0.0f;
}

__global__ void setup_kernel(const float* __restrict__ mu_raw,
                             const float* __restrict__ Dmu_raw,
                             const float* __restrict__ T0mu_raw,
                             const float* __restrict__ Ly_raw,
                             const float* __restrict__ xo_raw,
                             const float* __restrict__ yo_raw,
                             float* __restrict__ wsA,
                             float* __restrict__ wsW,
                             float* __restrict__ wsS)
{
    int id = blockIdx.x * blockDim.x + threadIdx.x;
    if (id >= NMODES) return;

    const float KF   = 1.0f / 44100.0f;
    const float PI_F = (float)M_PI;
    const double om2sq = (2.0 * M_PI * 500.0) * (2.0 * M_PI * 500.0);
    const float ALPHA_F = (float)(3.0 * M_LN10 / om2sq * (om2sq / 6.0));
    const float BETA_F  = (float)(3.0 * M_LN10 / om2sq * (1.0 - 1.0 / 6.0));
    const float MAX_OM_F = (float)(10000.0 * 2.0 * M_PI);
    const float MIN_OM_F = (float)(20.0 * 2.0 * M_PI);
    const float KK_F = (float)((1.0 / 44100.0) * (1.0 / 44100.0));

    float mu   = (softplusf(mu_raw[0])   + 1e-4f) * 2.43f;
    float Dmu  = (softplusf(Dmu_raw[0])  + 1e-4f) * 0.002452f;
    float T0mu = (softplusf(T0mu_raw[0]) + 1e-4f) * 0.004115f;
    float Ly   = 1.1f + 2.9f * sigmoidf(Ly_raw[0]);
    float xo   = 0.245f + 0.255f * sigmoidf(xo_raw[0]);                 // 0.49*LX + 0.51*LX*sg
    float yo   = __fadd_rn(__fmul_rn(0.51f, Ly),
                           __fmul_rn(__fmul_rn(0.49f, Ly), sigmoidf(yo_raw[0])));

    float mf = (float)(id / 80 + 1);
    float nf = (float)(id % 80 + 1);

    // g1 = (m*pi/LX)^2 + (n*pi/Ly)^2, LX = 0.5 (div by 0.5 == *2, exact)
    float am = __fmul_rn(__fmul_rn(mf, PI_F), 2.0f);
    float bn = __fdiv_rn(__fmul_rn(nf, PI_F), Ly);
    float g1 = __fadd_rn(__fmul_rn(am, am), __fmul_rn(bn, bn));
    float omega_sq = __fadd_rn(__fmul_rn(T0mu, g1),
                               __fmul_rn(__fmul_rn(Dmu, g1), g1));
    float omega = sqrtf(fmaxf(omega_sq, 0.0f));
    float valid = (omega <= MAX_OM_F && omega >= MIN_OM_F) ? 1.0f : 0.0f;

    // InW = cos(xi*pi*m/LX) * cos(yi*pi*n/Ly), xi = 0.05, yi = 0.1*Ly
    float xi_pi = (float)(0.05 * M_PI);
    float yi = __fmul_rn(0.1f, Ly);
    float InW = __fmul_rn(
        cosf(__fmul_rn(__fmul_rn(xi_pi, mf), 2.0f)),
        cosf(__fdiv_rn(__fmul_rn(__fmul_rn(yi, PI_F), nf), Ly)));
    float OutW = __fmul_rn(
        cosf(__fmul_rn(__fmul_rn(__fmul_rn(xo, PI_F), mf), 2.0f)),
        cosf(__fdiv_rn(__fmul_rn(__fmul_rn(yo, PI_F), nf), Ly)));

    float sigma = __fadd_rn(ALPHA_F, __fmul_rn(BETA_F, __fmul_rn(omega, omega)));
    float ms = __fmul_rn(__fmul_rn(__fmul_rn(0.25f, mu), 0.5f), Ly);
    float P = __fmul_rn(
        __fdiv_rn(__fmul_rn(__fmul_rn(__fmul_rn(OutW, InW), KK_F),
                            expf(__fmul_rn(-sigma, KF))),
                  ms),
        valid);
    float den = __fadd_rn(sinf(__fmul_rn(omega, KF)), 1e-8f);
    float A = __fdiv_rn(P, den);

    wsA[id] = A;
    wsW[id] = omega;
    wsS[id] = sigma;
}

__global__ __launch_bounds__(TB) void accum_kernel(const float* __restrict__ wsA,
                                                   const float* __restrict__ wsW,
                                                   const float* __restrict__ wsS,
                                                   float* __restrict__ out, int T)
{
    __shared__ float sA[CHUNK], sW[CHUNK], sS[CHUNK];
    int base = blockIdx.y * CHUNK;
    for (int i = threadIdx.x; i < CHUNK; i += TB) {
        sA[i] = wsA[base + i];
        sW[i] = wsW[base + i];
        sS[i] = wsS[base + i];
    }
    __syncthreads();

    int t = blockIdx.x * TB + threadIdx.x;
    if (t >= T) return;

    float tf  = (float)t;
    float tm1 = __fsub_rn(tf, 1.0f);
    const float  KF         = 1.0f / 44100.0f;
    const double TWO_PI     = 6.283185307179586476925286766559;
    const double INV_TWO_PI = 0.15915494309189533576888376337251;

    float acc = 0.0f;
    for (int i = 0; i < CHUNK; ++i) {
        float A = sA[i];
        if (A == 0.0f) continue;   // block-uniform branch: all threads share i
        float w = sW[i];
        float s = sS[i];
        // sine_num = sin((t * omega) * K) — fp32 arg like the reference,
        // then exact-in-double range reduction mod 2*pi, HW sin on |r|<=pi
        float arg = __fmul_rn(__fmul_rn(tf, w), KF);
        double ad = (double)arg;
        double q  = rint(ad * INV_TWO_PI);
        float r   = (float)fma(-q, TWO_PI, ad);
        float sn  = __sinf(r);
        // decay = exp((-sigma * (t-1)) * K)
        float decay = __expf(__fmul_rn(__fmul_rn(-s, tm1), KF));
        acc = __fmaf_rn(__fmul_rn(A, decay), sn, acc);
    }
    atomicAdd(&out[t], acc);
}

__global__ void peak_kernel(const float* __restrict__ out, float* __restrict__ peak, int T)
{
    __shared__ float red[256];
    float mx = 0.0f;
    for (int i = threadIdx.x; i < T; i += 256) mx = fmaxf(mx, fabsf(out[i]));
    red[threadIdx.x] = mx;
    __syncthreads();
    for (int s = 128; s > 0; s >>= 1) {
        if ((int)threadIdx.x < s)
            red[threadIdx.x] = fmaxf(red[threadIdx.x], red[threadIdx.x + s]);
        __syncthreads();
    }
    if (threadIdx.x == 0) peak[0] = red[0] + 1e-8f;
}

__global__ void scale_kernel(float* __restrict__ out, const float* __restrict__ peak, int T)
{
    int i = blockIdx.x * blockDim.x + threadIdx.x;
    if (i < T) out[i] = __fdiv_rn(out[i], peak[0]);
}

extern "C" void kernel_launch(void* const* d_in, const int* in_sizes, int n_in,
                              void* d_out, int out_size, void* d_ws, size_t ws_size,
                              hipStream_t stream)
{
    const float* mu   = (const float*)d_in[0];
    const float* Dmu  = (const float*)d_in[1];
    const float* T0mu = (const float*)d_in[2];
    const float* Lyr  = (const float*)d_in[3];
    const float* xor_ = (const float*)d_in[4];
    const float* yor_ = (const float*)d_in[5];
    float* out = (float*)d_out;

    float* ws     = (float*)d_ws;
    float* wsA    = ws;
    float* wsW    = ws + NMODES;
    float* wsS    = ws + 2 * NMODES;
    float* wsPeak = ws + 3 * NMODES;

    int T = out_size;            // == num_samples
    int gridT = (T + TB - 1) / TB;

    zero_kernel<<<gridT, TB, 0, stream>>>(out, T);
    setup_kernel<<<(NMODES + TB - 1) / TB, TB, 0, stream>>>(mu, Dmu, T0mu, Lyr, xor_, yor_,
                                                            wsA, wsW, wsS);
    accum_kernel<<<dim3(gridT, CHUNKS), TB, 0, stream>>>(wsA, wsW, wsS, out, T);
    peak_kernel<<<1, 256, 0, stream>>>(out, wsPeak, T);
    scale_kernel<<<gridT, TB, 0, stream>>>(out, wsPeak, T);
}

// Round 2
// 113.338 us; speedup vs baseline: 1.6572x; 1.6572x over previous
//
#include <hip/hip_runtime.h>
#include <math.h>

#define NMODES  6400
#define TB      256
#define MPT     5                 // modes per thread
#define MG      5                 // mode groups: NMODES / (TB*MPT)
#define TC      87                // samples per time-chunk
#define TCHUNKS 254               // ceil(22050/87)

static __device__ __forceinline__ float softplusf(float x) {
    return log1pf(expf(-fabsf(x))) + fmaxf(x, 0.0f);
}
static __device__ __forceinline__ float sigmoidf(float x) {
    return 1.0f / (1.0f + expf(-x));
}

__global__ void zero_kernel(float* __restrict__ out, float* __restrict__ peak, int T) {
    int i = blockIdx.x * blockDim.x + threadIdx.x;
    if (i < T) out[i] = 0.0f;
    if (i == 0) peak[0] = 0.0f;
}

// per-mode constants: A (amplitude incl. validity), omega, sigma, cwd, swd
__global__ void setup_kernel(const float* __restrict__ mu_raw,
                             const float* __restrict__ Dmu_raw,
                             const float* __restrict__ T0mu_raw,
                             const float* __restrict__ Ly_raw,
                             const float* __restrict__ xo_raw,
                             const float* __restrict__ yo_raw,
                             float* __restrict__ wsA,
                             float* __restrict__ wsW,
                             float* __restrict__ wsS,
                             float* __restrict__ wsCW,
                             float* __restrict__ wsSW)
{
    int id = blockIdx.x * blockDim.x + threadIdx.x;
    if (id >= NMODES) return;

    const float KF   = 1.0f / 44100.0f;
    const float PI_F = (float)M_PI;
    const double om2sq = (2.0 * M_PI * 500.0) * (2.0 * M_PI * 500.0);
    const float ALPHA_F = (float)(3.0 * M_LN10 / om2sq * (om2sq / 6.0));
    const float BETA_F  = (float)(3.0 * M_LN10 / om2sq * (1.0 - 1.0 / 6.0));
    const float MAX_OM_F = (float)(10000.0 * 2.0 * M_PI);
    const float MIN_OM_F = (float)(20.0 * 2.0 * M_PI);
    const float KK_F = (float)((1.0 / 44100.0) * (1.0 / 44100.0));

    float mu   = (softplusf(mu_raw[0])   + 1e-4f) * 2.43f;
    float Dmu  = (softplusf(Dmu_raw[0])  + 1e-4f) * 0.002452f;
    float T0mu = (softplusf(T0mu_raw[0]) + 1e-4f) * 0.004115f;
    float Ly   = 1.1f + 2.9f * sigmoidf(Ly_raw[0]);
    float xo   = 0.245f + 0.255f * sigmoidf(xo_raw[0]);
    float yo   = __fadd_rn(__fmul_rn(0.51f, Ly),
                           __fmul_rn(__fmul_rn(0.49f, Ly), sigmoidf(yo_raw[0])));

    float mf = (float)(id / 80 + 1);
    float nf = (float)(id % 80 + 1);

    float am = __fmul_rn(__fmul_rn(mf, PI_F), 2.0f);
    float bn = __fdiv_rn(__fmul_rn(nf, PI_F), Ly);
    float g1 = __fadd_rn(__fmul_rn(am, am), __fmul_rn(bn, bn));
    float omega_sq = __fadd_rn(__fmul_rn(T0mu, g1),
                               __fmul_rn(__fmul_rn(Dmu, g1), g1));
    float omega = sqrtf(fmaxf(omega_sq, 0.0f));
    float valid = (omega <= MAX_OM_F && omega >= MIN_OM_F) ? 1.0f : 0.0f;

    float xi_pi = (float)(0.05 * M_PI);
    float yi = __fmul_rn(0.1f, Ly);
    float InW = __fmul_rn(
        cosf(__fmul_rn(__fmul_rn(xi_pi, mf), 2.0f)),
        cosf(__fdiv_rn(__fmul_rn(__fmul_rn(yi, PI_F), nf), Ly)));
    float OutW = __fmul_rn(
        cosf(__fmul_rn(__fmul_rn(__fmul_rn(xo, PI_F), mf), 2.0f)),
        cosf(__fdiv_rn(__fmul_rn(__fmul_rn(yo, PI_F), nf), Ly)));

    float sigma = __fadd_rn(ALPHA_F, __fmul_rn(BETA_F, __fmul_rn(omega, omega)));
    float ms = __fmul_rn(__fmul_rn(__fmul_rn(0.25f, mu), 0.5f), Ly);
    float P = __fmul_rn(
        __fdiv_rn(__fmul_rn(__fmul_rn(__fmul_rn(OutW, InW), KK_F),
                            expf(__fmul_rn(-sigma, KF))),
                  ms),
        valid);
    float den = __fadd_rn(sinf(__fmul_rn(omega, KF)), 1e-8f);
    float A = __fdiv_rn(P, den);

    // recurrence rotation constants, computed in double
    const double Kd = 1.0 / 44100.0;
    double th = (double)omega * Kd;
    double dd = exp(-(double)sigma * Kd);
    wsA[id]  = A;
    wsW[id]  = omega;
    wsS[id]  = sigma;
    wsCW[id] = (float)(dd * cos(th));
    wsSW[id] = (float)(dd * sin(th));
}

// Each thread owns MPT modes; per sample t: rotate states (4 fma/mode),
// wave-reduce the 320-mode partial, one atomicAdd per wave per t.
__global__ __launch_bounds__(TB) void accum_kernel(const float* __restrict__ wsA,
                                                   const float* __restrict__ wsW,
                                                   const float* __restrict__ wsS,
                                                   const float* __restrict__ wsCW,
                                                   const float* __restrict__ wsSW,
                                                   float* __restrict__ out, int T)
{
    const int tid  = threadIdx.x;
    const int t0   = blockIdx.x * TC;
    const int base = blockIdx.y * (TB * MPT);

    const float  KF     = 1.0f / 44100.0f;
    const double Kd     = 1.0 / 44100.0;
    const double TWO_PI = 6.283185307179586476925286766559;
    const double I2PI   = 0.15915494309189533576888376337251;

    float S[MPT], C[MPT], CW[MPT], SW[MPT];
    #pragma unroll
    for (int j = 0; j < MPT; ++j) {
        int m = base + j * TB + tid;
        float A  = wsA[m];
        float w  = wsW[m];
        float sg = wsS[m];
        CW[j] = wsCW[m];
        SW[j] = wsSW[m];
        // exact init at t0: phase reduced in double, env in float
        double ph = (double)t0 * (double)w * Kd;
        double q  = rint(ph * I2PI);
        float  r  = (float)fma(-q, TWO_PI, ph);
        float  s0 = __sinf(r);
        float  c0 = __cosf(r);
        float env = A * __expf(-sg * (float)(t0 - 1) * KF);
        S[j] = env * s0;
        C[j] = env * c0;
    }

    #pragma unroll 1
    for (int tt = 0; tt < TC; ++tt) {
        int t = t0 + tt;
        float acc = S[0];
        #pragma unroll
        for (int j = 1; j < MPT; ++j) acc += S[j];
        // 64-lane butterfly reduction
        #pragma unroll
        for (int off = 32; off > 0; off >>= 1)
            acc += __shfl_xor(acc, off, 64);
        if ((tid & 63) == 0 && t < T) atomicAdd(&out[t], acc);
        // rotate all states
        #pragma unroll
        for (int j = 0; j < MPT; ++j) {
            float nS = __fmaf_rn(S[j], CW[j],  C[j] * SW[j]);
            float nC = __fmaf_rn(C[j], CW[j], -(S[j] * SW[j]));
            S[j] = nS;
            C[j] = nC;
        }
    }
}

__global__ void peak_kernel(const float* __restrict__ out, float* __restrict__ peak, int T)
{
    int i = blockIdx.x * blockDim.x + threadIdx.x;
    float v = (i < T) ? fabsf(out[i]) : 0.0f;
    #pragma unroll
    for (int off = 32; off > 0; off >>= 1)
        v = fmaxf(v, __shfl_xor(v, off, 64));
    __shared__ float red[4];
    int lane = threadIdx.x & 63, wv = threadIdx.x >> 6;
    if (lane == 0) red[wv] = v;
    __syncthreads();
    if (threadIdx.x == 0) {
        float mx = fmaxf(fmaxf(red[0], red[1]), fmaxf(red[2], red[3]));
        atomicMax((unsigned int*)peak, __float_as_uint(mx)); // all values >= 0
    }
}

__global__ void scale_kernel(float* __restrict__ out, const float* __restrict__ peak, int T)
{
    int i = blockIdx.x * blockDim.x + threadIdx.x;
    if (i < T) out[i] = __fdiv_rn(out[i], peak[0] + 1e-8f);
}

extern "C" void kernel_launch(void* const* d_in, const int* in_sizes, int n_in,
                              void* d_out, int out_size, void* d_ws, size_t ws_size,
                              hipStream_t stream)
{
    const float* mu   = (const float*)d_in[0];
    const float* Dmu  = (const float*)d_in[1];
    const float* T0mu = (const float*)d_in[2];
    const float* Lyr  = (const float*)d_in[3];
    const float* xor_ = (const float*)d_in[4];
    const float* yor_ = (const float*)d_in[5];
    float* out = (float*)d_out;

    float* ws     = (float*)d_ws;
    float* wsA    = ws;
    float* wsW    = ws + NMODES;
    float* wsS    = ws + 2 * NMODES;
    float* wsCW   = ws + 3 * NMODES;
    float* wsSW   = ws + 4 * NMODES;
    float* wsPeak = ws + 5 * NMODES;

    int T = out_size;
    int gridT = (T + TB - 1) / TB;

    zero_kernel<<<gridT, TB, 0, stream>>>(out, wsPeak, T);
    setup_kernel<<<(NMODES + TB - 1) / TB, TB, 0, stream>>>(mu, Dmu, T0mu, Lyr, xor_, yor_,
                                                            wsA, wsW, wsS, wsCW, wsSW);
    accum_kernel<<<dim3(TCHUNKS, MG), TB, 0, stream>>>(wsA, wsW, wsS, wsCW, wsSW, out, T);
    peak_kernel<<<gridT, TB, 0, stream>>>(out, wsPeak, T);
    scale_kernel<<<gridT, TB, 0, stream>>>(out, wsPeak, T);
}

// Round 3
// 102.951 us; speedup vs baseline: 1.8244x; 1.1009x over previous
//
#include <hip/hip_runtime.h>
#include <math.h>

#define NMODES 6400
#define TB     256
#define MPT    25                 // modes per thread: TB*MPT == NMODES (one block = all modes)
#define TC     44                 // samples per time-chunk

static __device__ __forceinline__ float softplusf(float x) {
    return log1pf(expf(-fabsf(x))) + fmaxf(x, 0.0f);
}
static __device__ __forceinline__ float sigmoidf(float x) {
    return 1.0f / (1.0f + expf(-x));
}

// per-mode constants: A (amplitude incl. validity), omega, sigma, cwd, swd
__global__ void setup_kernel(const float* __restrict__ mu_raw,
                             const float* __restrict__ Dmu_raw,
                             const float* __restrict__ T0mu_raw,
                             const float* __restrict__ Ly_raw,
                             const float* __restrict__ xo_raw,
                             const float* __restrict__ yo_raw,
                             float* __restrict__ wsA,
                             float* __restrict__ wsW,
                             float* __restrict__ wsS,
                             float* __restrict__ wsCW,
                             float* __restrict__ wsSW)
{
    int id = blockIdx.x * blockDim.x + threadIdx.x;
    if (id >= NMODES) return;

    const float KF   = 1.0f / 44100.0f;
    const float PI_F = (float)M_PI;
    const double om2sq = (2.0 * M_PI * 500.0) * (2.0 * M_PI * 500.0);
    const float ALPHA_F = (float)(3.0 * M_LN10 / om2sq * (om2sq / 6.0));
    const float BETA_F  = (float)(3.0 * M_LN10 / om2sq * (1.0 - 1.0 / 6.0));
    const float MAX_OM_F = (float)(10000.0 * 2.0 * M_PI);
    const float MIN_OM_F = (float)(20.0 * 2.0 * M_PI);
    const float KK_F = (float)((1.0 / 44100.0) * (1.0 / 44100.0));

    float mu   = (softplusf(mu_raw[0])   + 1e-4f) * 2.43f;
    float Dmu  = (softplusf(Dmu_raw[0])  + 1e-4f) * 0.002452f;
    float T0mu = (softplusf(T0mu_raw[0]) + 1e-4f) * 0.004115f;
    float Ly   = 1.1f + 2.9f * sigmoidf(Ly_raw[0]);
    float xo   = 0.245f + 0.255f * sigmoidf(xo_raw[0]);
    float yo   = __fadd_rn(__fmul_rn(0.51f, Ly),
                           __fmul_rn(__fmul_rn(0.49f, Ly), sigmoidf(yo_raw[0])));

    float mf = (float)(id / 80 + 1);
    float nf = (float)(id % 80 + 1);

    float am = __fmul_rn(__fmul_rn(mf, PI_F), 2.0f);
    float bn = __fdiv_rn(__fmul_rn(nf, PI_F), Ly);
    float g1 = __fadd_rn(__fmul_rn(am, am), __fmul_rn(bn, bn));
    float omega_sq = __fadd_rn(__fmul_rn(T0mu, g1),
                               __fmul_rn(__fmul_rn(Dmu, g1), g1));
    float omega = sqrtf(fmaxf(omega_sq, 0.0f));
    float valid = (omega <= MAX_OM_F && omega >= MIN_OM_F) ? 1.0f : 0.0f;

    float xi_pi = (float)(0.05 * M_PI);
    float yi = __fmul_rn(0.1f, Ly);
    float InW = __fmul_rn(
        cosf(__fmul_rn(__fmul_rn(xi_pi, mf), 2.0f)),
        cosf(__fdiv_rn(__fmul_rn(__fmul_rn(yi, PI_F), nf), Ly)));
    float OutW = __fmul_rn(
        cosf(__fmul_rn(__fmul_rn(__fmul_rn(xo, PI_F), mf), 2.0f)),
        cosf(__fdiv_rn(__fmul_rn(__fmul_rn(yo, PI_F), nf), Ly)));

    float sigma = __fadd_rn(ALPHA_F, __fmul_rn(BETA_F, __fmul_rn(omega, omega)));
    float ms = __fmul_rn(__fmul_rn(__fmul_rn(0.25f, mu), 0.5f), Ly);
    float P = __fmul_rn(
        __fdiv_rn(__fmul_rn(__fmul_rn(__fmul_rn(OutW, InW), KK_F),
                            expf(__fmul_rn(-sigma, KF))),
                  ms),
        valid);
    float den = __fadd_rn(sinf(__fmul_rn(omega, KF)), 1e-8f);
    float A = __fdiv_rn(P, den);

    const double Kd = 1.0 / 44100.0;
    double th = (double)omega * Kd;
    double dd = exp(-(double)sigma * Kd);
    wsA[id]  = A;
    wsW[id]  = omega;
    wsS[id]  = sigma;
    wsCW[id] = (float)(dd * cos(th));
    wsSW[id] = (float)(dd * sin(th));
}

// One block = ALL 6400 modes for a TC-sample time range. Each thread owns 25
// modes (phasor recurrence: 4 FMA + 1 add per mode-step). Per t: tree-sum,
// 64-lane butterfly, cross-wave combine in LDS, single plain store. No atomics.
__global__ __launch_bounds__(TB, 2) void accum_kernel(const float* __restrict__ wsA,
                                                      const float* __restrict__ wsW,
                                                      const float* __restrict__ wsS,
                                                      const float* __restrict__ wsCW,
                                                      const float* __restrict__ wsSW,
                                                      float* __restrict__ out, int T)
{
    const int tid = threadIdx.x;
    const int t0  = blockIdx.x * TC;

    const float  KF     = 1.0f / 44100.0f;
    const double Kd     = 1.0 / 44100.0;
    const double TWO_PI = 6.283185307179586476925286766559;
    const double I2PI   = 0.15915494309189533576888376337251;

    __shared__ float sRed[4][TC];

    float S[MPT], C[MPT], CW[MPT], SW[MPT];
    #pragma unroll
    for (int j = 0; j < MPT; ++j) {
        int m = j * TB + tid;
        float A  = wsA[m];
        float w  = wsW[m];
        float sg = wsS[m];
        CW[j] = wsCW[m];
        SW[j] = wsSW[m];
        double ph = (double)t0 * (double)w * Kd;
        double q  = rint(ph * I2PI);
        float  r  = (float)fma(-q, TWO_PI, ph);
        float env = A * __expf(-sg * (float)(t0 - 1) * KF);
        S[j] = env * __sinf(r);
        C[j] = env * __cosf(r);
    }

    const int wv = tid >> 6, lane = tid & 63;

    #pragma unroll 1
    for (int tt = 0; tt < TC; ++tt) {
        // 4-way interleaved tree sum of current S[] (short dep chain)
        float a0 = S[0], a1 = S[1], a2 = S[2], a3 = S[3];
        #pragma unroll
        for (int j = 4; j < MPT; j += 4) a0 += S[j];
        #pragma unroll
        for (int j = 5; j < MPT; j += 4) a1 += S[j];
        #pragma unroll
        for (int j = 6; j < MPT; j += 4) a2 += S[j];
        #pragma unroll
        for (int j = 7; j < MPT; j += 4) a3 += S[j];
        float acc = (a0 + a1) + (a2 + a3);
        // rotate states (independent of the butterfly -> overlaps shfl latency)
        #pragma unroll
        for (int j = 0; j < MPT; ++j) {
            float nS = __fmaf_rn(S[j], CW[j],  C[j] * SW[j]);
            float nC = __fmaf_rn(C[j], CW[j], -(S[j] * SW[j]));
            S[j] = nS;
            C[j] = nC;
        }
        #pragma unroll
        for (int off = 32; off > 0; off >>= 1)
            acc += __shfl_xor(acc, off, 64);
        if (lane == 0) sRed[wv][tt] = acc;
    }
    __syncthreads();
    for (int tt = tid; tt < TC; tt += TB) {
        int t = t0 + tt;
        if (t < T)
            out[t] = (sRed[0][tt] + sRed[1][tt]) + (sRed[2][tt] + sRed[3][tt]);
    }
}

// Single block: find peak |out|, then divide through. Fuses peak+scale.
__global__ __launch_bounds__(1024) void norm_kernel(float* __restrict__ out, int T)
{
    __shared__ float red[16];
    __shared__ float peakv;
    float mx = 0.0f;
    for (int i = threadIdx.x; i < T; i += 1024) mx = fmaxf(mx, fabsf(out[i]));
    #pragma unroll
    for (int off = 32; off > 0; off >>= 1)
        mx = fmaxf(mx, __shfl_xor(mx, off, 64));
    int lane = threadIdx.x & 63, wv = threadIdx.x >> 6;
    if (lane == 0) red[wv] = mx;
    __syncthreads();
    if (threadIdx.x == 0) {
        float m = red[0];
        #pragma unroll
        for (int i = 1; i < 16; ++i) m = fmaxf(m, red[i]);
        peakv = m + 1e-8f;
    }
    __syncthreads();
    float pk = peakv;
    for (int i = threadIdx.x; i < T; i += 1024) out[i] = __fdiv_rn(out[i], pk);
}

extern "C" void kernel_launch(void* const* d_in, const int* in_sizes, int n_in,
                              void* d_out, int out_size, void* d_ws, size_t ws_size,
                              hipStream_t stream)
{
    const float* mu   = (const float*)d_in[0];
    const float* Dmu  = (const float*)d_in[1];
    const float* T0mu = (const float*)d_in[2];
    const float* Lyr  = (const float*)d_in[3];
    const float* xor_ = (const float*)d_in[4];
    const float* yor_ = (const float*)d_in[5];
    float* out = (float*)d_out;

    float* ws   = (float*)d_ws;
    float* wsA  = ws;
    float* wsW  = ws + NMODES;
    float* wsS  = ws + 2 * NMODES;
    float* wsCW = ws + 3 * NMODES;
    float* wsSW = ws + 4 * NMODES;

    int T = out_size;
    int tchunks = (T + TC - 1) / TC;

    setup_kernel<<<(NMODES + TB - 1) / TB, TB, 0, stream>>>(mu, Dmu, T0mu, Lyr, xor_, yor_,
                                                            wsA, wsW, wsS, wsCW, wsSW);
    accum_kernel<<<tchunks, TB, 0, stream>>>(wsA, wsW, wsS, wsCW, wsSW, out, T);
    norm_kernel<<<1, 1024, 0, stream>>>(out, T);
}